// Round 3
// baseline (155.733 us; speedup 1.0000x reference)
//
#include <hip/hip_runtime.h>
#include <math.h>

// Problem constants
#define NPIX   131072      // 32 * 64 * 64 pixels
#define KCODES 512
#define DDIM   64
#define HWSZ   4096        // 64*64
#define NELEM  8388608     // NPIX * DDIM

// d_out layout (fp32): [0]=loss, [1..1+NELEM)=q_nchw, [1+NELEM]=perplexity,
// [2+NELEM .. 2+2*NELEM)=q_nhwc flat
#define OUT_NCHW_OFF 1
#define OUT_PERP_IDX (1 + NELEM)
#define OUT_NHWC_OFF (2 + NELEM)

// ws layout (fp32 words): [0]=loss, [16..528)=|e|^2, [544..1056)=counts(uint),
// [1056]=ticket, [2048..) = e bf16 hi/lo fragments in MFMA B-layout (128KB)
#define WS_NRM_OFF  16
#define WS_CNT_OFF  544
#define WS_TICKET   1056
#define WS_FRAG_F32 2048

#define NBLOCKS (NPIX / 128)   // 1024 blocks, 128 pixels each

typedef __bf16 bf16x8 __attribute__((ext_vector_type(8)));
typedef float  f32x4  __attribute__((ext_vector_type(4)));

__device__ __forceinline__ void glds16(const void* g, void* l) {
    __builtin_amdgcn_global_load_lds(
        (const __attribute__((address_space(1))) void*)g,
        (__attribute__((address_space(3))) void*)l, 16, 0, 0);
}

// Fused prep (memset + norms + pack in one dispatch). Thread tid =
// [ctile(32)][kstep(2)][h(2)][lane(64)] packs e into bf16 hi/lo MFMA
// B-fragments (16x16x32: B[k][n], n=lane&15, k=(lane>>4)*8+j); 16B coalesced.
// tid<512 computes |e|^2; tid in [512,1024) zeros counts; tid 0 zeros loss;
// tid 1024 zeros the last-block ticket.
__global__ __launch_bounds__(256) void vq_prep(const float* __restrict__ emb,
                                               float* __restrict__ ws) {
    int tid  = blockIdx.x * 256 + threadIdx.x;   // 0..8191
    if (tid == 0) ws[0] = 0.f;
    if (tid == 2 * KCODES) reinterpret_cast<unsigned*>(ws)[WS_TICKET] = 0u;
    if (tid < KCODES) {
        const float4* e4 = reinterpret_cast<const float4*>(emb + tid * DDIM);
        float s = 0.f;
#pragma unroll
        for (int i = 0; i < 16; ++i) {
            float4 v = e4[i];
            s = fmaf(v.x, v.x, s); s = fmaf(v.y, v.y, s);
            s = fmaf(v.z, v.z, s); s = fmaf(v.w, v.w, s);
        }
        ws[WS_NRM_OFF + tid] = s;
    } else if (tid < 2 * KCODES) {
        reinterpret_cast<unsigned*>(ws)[WS_CNT_OFF + (tid - KCODES)] = 0u;
    }

    int lane = tid & 63;
    int h    = (tid >> 6) & 1;
    int ks   = (tid >> 7) & 1;
    int ct   = tid >> 8;                         // 0..31
    int code = ct * 16 + (lane & 15);
    int d0   = ks * 32 + ((lane >> 4) & 3) * 8;
    const float* src = emb + code * DDIM + d0;
    unsigned short us[8];
#pragma unroll
    for (int j = 0; j < 8; ++j) {
        float f = src[j];
        __bf16 hb = (__bf16)f;                       // RTN
        if (h == 0) {
            us[j] = __builtin_bit_cast(unsigned short, hb);
        } else {
            __bf16 lb = (__bf16)(f - (float)hb);
            us[j] = __builtin_bit_cast(unsigned short, lb);
        }
    }
    uint4 v;
    v.x = us[0] | ((unsigned)us[1] << 16);
    v.y = us[2] | ((unsigned)us[3] << 16);
    v.z = us[4] | ((unsigned)us[5] << 16);
    v.w = us[6] | ((unsigned)us[7] << 16);
    reinterpret_cast<uint4*>(ws + WS_FRAG_F32)[tid] = v;
}

// Main. R2 lesson: the binding constraint was GRID SIZE (512 blocks = 2/CU),
// not LDS/VGPR. Now: 1024 blocks x 128 pixels (32 px/wave, pt=2) -> 4
// blocks/CU. B-fragments are staged per-block into LDS (double-buffered 2x8KB,
// async global_load_lds, 2-phase: issue next-chunk stage BEFORE compute,
// one barrier per chunk) -> B latency hidden, B regs freed (fits 128-VGPR cap
// of (256,4) with ~115 live). Fragments reach MFMA bit-identical -> identical
// argmin -> identical outputs. vq_fin fused in via last-block ticket.
__global__ __launch_bounds__(256, 4) void vq_main(const float* __restrict__ in,
                                                  const float* __restrict__ emb,
                                                  float* __restrict__ out,
                                                  float* __restrict__ ws) {
    // smem_big: main loop = B double-buffer (2 x 8KB); epilogue = q transpose
    // tile [64][65] (16.6KB). Aliased: main loop fully done before epilogue.
    __shared__ __align__(16) float smem_big[64 * 65];
    __shared__ float    x2_lds[128];
    __shared__ float    nrm_lds[KCODES];
    __shared__ int      idx_lds[128];
    __shared__ unsigned cnt_lds[KCODES];
    __shared__ float    red_tot;
    __shared__ int      is_last;
    __shared__ double   rd[4];

    const int t = threadIdx.x;
    const int l = t & 63, wid = t >> 6;   // wave handles pixels [wid*32, +32)
    cnt_lds[t] = 0u; cnt_lds[t + 256] = 0u;
    if (t == 0) red_tot = 0.f;

    const int pix0 = blockIdx.x << 7;     // 128 px per block
    const int b    = pix0 >> 12;
    const int hwb  = pix0 & (HWSZ - 1);

    char* bst = reinterpret_cast<char*>(smem_big);
    const char* fragbytes = reinterpret_cast<const char*>(ws + WS_FRAG_F32);

    // Issue async stage of B chunk 0 FIRST: latency hides under A-frag load.
    // Wave w stages bytes [w*2048, w*2048+2048) of the 8KB chunk (2 x 1KB
    // issues; LDS dest = wave-uniform base + lane*16, matching linear layout).
    {
        const char* s0 = fragbytes + (wid << 11) + (l << 4);
        glds16(s0,        bst + (wid << 11));
        glds16(s0 + 1024, bst + (wid << 11) + 1024);
    }

    nrm_lds[t]       = ws[WS_NRM_OFF + t];
    nrm_lds[t + 256] = ws[WS_NRM_OFF + t + 256];

    // A-fragments (A[m][k]: m=lane&15, k=(lane>>4)*8+j), hi/lo bf16 split,
    // loaded straight from global NCHW. |x|^2 via xor-16/32 reduce
    // (lanes l, l^16, l^32, l^48 cover all 64 channels of pixel hw).
    const float* base = in + b * (DDIM * HWSZ) + hwb + wid * 32;
    bf16x8 a_hi[2][2], a_lo[2][2];
    float x2p[2];
#pragma unroll
    for (int pt = 0; pt < 2; ++pt) {
        const int hw = pt * 16 + (l & 15);
        float s = 0.f;
#pragma unroll
        for (int ks = 0; ks < 2; ++ks) {
            const int d0 = ks * 32 + ((l >> 4) & 3) * 8;
            const float* pp = base + hw + d0 * HWSZ;
            bf16x8 h8, l8;
#pragma unroll
            for (int j = 0; j < 8; ++j) {
                float f = pp[j * HWSZ];
                s = fmaf(f, f, s);
                __bf16 hb = (__bf16)f;
                h8[j] = hb;
                l8[j] = (__bf16)(f - (float)hb);
            }
            a_hi[pt][ks] = h8; a_lo[pt][ks] = l8;
        }
        s += __shfl_xor(s, 16, 64);
        s += __shfl_xor(s, 32, 64);
        x2p[pt] = s;
    }
    if (l < 16) {
        x2_lds[wid * 32 + l]      = x2p[0];
        x2_lds[wid * 32 + 16 + l] = x2p[1];
    }
    __syncthreads();   // chunk0 staged (vmcnt drained) + nrm/cnt/x2 ready

    float best[2][4]; int bidx[2][4];
#pragma unroll
    for (int pt = 0; pt < 2; ++pt)
#pragma unroll
    for (int r = 0; r < 4; ++r) { best[pt][r] = 3.4e38f; bidx[pt][r] = 0; }

    int cur = 0;
#pragma unroll 1
    for (int c = 0; c < 16; ++c) {
        // 2-phase: issue next chunk's async stage before computing current.
        if (c + 1 < 16) {
            const char* s0 = fragbytes + ((size_t)(c + 1) << 13) + (wid << 11) + (l << 4);
            char* d0 = bst + ((cur ^ 1) << 13) + (wid << 11);
            glds16(s0,        d0);
            glds16(s0 + 1024, d0 + 1024);
        }
        // 8 B-frags (ct2 x ks2 x h2) from LDS, lane l at byte f*1024 + l*16.
        uint4 bf[8];
#pragma unroll
        for (int i = 0; i < 8; ++i)
            bf[i] = *reinterpret_cast<const uint4*>(bst + (cur << 13) + (i << 10) + (l << 4));

        // 32 pix x 32 codes: 4 C-tiles, 4-term bf16 split accumulated in fp32
        f32x4 acc[2][2];
#pragma unroll
        for (int pt = 0; pt < 2; ++pt)
#pragma unroll
        for (int ct = 0; ct < 2; ++ct) {
            f32x4 a = {0.f, 0.f, 0.f, 0.f};
#pragma unroll
            for (int ks = 0; ks < 2; ++ks) {
                bf16x8 bh = __builtin_bit_cast(bf16x8, bf[ct * 4 + ks * 2 + 0]);
                bf16x8 bl = __builtin_bit_cast(bf16x8, bf[ct * 4 + ks * 2 + 1]);
                a = __builtin_amdgcn_mfma_f32_16x16x32_bf16(a_hi[pt][ks], bh, a, 0, 0, 0);
                a = __builtin_amdgcn_mfma_f32_16x16x32_bf16(a_hi[pt][ks], bl, a, 0, 0, 0);
                a = __builtin_amdgcn_mfma_f32_16x16x32_bf16(a_lo[pt][ks], bh, a, 0, 0, 0);
                a = __builtin_amdgcn_mfma_f32_16x16x32_bf16(a_lo[pt][ks], bl, a, 0, 0, 0);
            }
            acc[pt][ct] = a;
        }
        // argmin update; C/D: col(code)=lane&15, row(pix)=(lane>>4)*4+reg
        const int cb = c << 5;
#pragma unroll
        for (int ct = 0; ct < 2; ++ct) {
            int code = cb + ct * 16 + (l & 15);
            float nv = nrm_lds[code];
#pragma unroll
            for (int pt = 0; pt < 2; ++pt)
#pragma unroll
            for (int r = 0; r < 4; ++r) {
                float d = fmaf(-2.f, acc[pt][ct][r], nv);
                if (d < best[pt][r]) { best[pt][r] = d; bidx[pt][r] = code; }
            }
        }
        // One barrier/chunk: next chunk's stage drained (syncthreads implies
        // vmcnt(0)), and all waves done reading buf before it's re-staged.
        __syncthreads();
        cur ^= 1;
    }

    // Cross-lane argmin within each 16-lane group (codes spread over lane&15);
    // (dist, then idx) min = exact first-min semantics.
#pragma unroll
    for (int off = 1; off < 16; off <<= 1) {
#pragma unroll
        for (int pt = 0; pt < 2; ++pt)
#pragma unroll
        for (int r = 0; r < 4; ++r) {
            float ob = __shfl_xor(best[pt][r], off, 64);
            int   oi = __shfl_xor(bidx[pt][r], off, 64);
            bool take = (ob < best[pt][r]) || (ob == best[pt][r] && oi < bidx[pt][r]);
            if (take) { best[pt][r] = ob; bidx[pt][r] = oi; }
        }
    }
    if ((l & 15) == 0) {
        int q = l >> 4;
        float lp = 0.f;
#pragma unroll
        for (int pt = 0; pt < 2; ++pt)
#pragma unroll
        for (int r = 0; r < 4; ++r) {
            int pixl = wid * 32 + pt * 16 + q * 4 + r;
            idx_lds[pixl] = bidx[pt][r];
            atomicAdd(&cnt_lds[bidx[pt][r]], 1u);
            lp += x2_lds[pixl] + best[pt][r];   // |x-e|^2 = x^2 + (|e|^2 - 2x.e)
        }
        atomicAdd(&red_tot, lp);
    }
    __syncthreads();

    if (t == 0) atomicAdd(ws, red_tot);
    unsigned* gcnt = reinterpret_cast<unsigned*>(ws) + WS_CNT_OFF;
    atomicAdd(gcnt + t, cnt_lds[t]);
    atomicAdd(gcnt + t + 256, cnt_lds[t + 256]);
    __syncthreads();   // all this block's global atomics drained (vmcnt 0)

    if (t == 0) {
        unsigned tk = __hip_atomic_fetch_add(
            reinterpret_cast<unsigned*>(ws) + WS_TICKET, 1u,
            __ATOMIC_ACQ_REL, __HIP_MEMORY_SCOPE_AGENT);
        is_last = (tk == NBLOCKS - 1);
    }

    // Epilogue: padded LDS tile (aliases B-staging) makes both NHWC and NCHW
    // writes coalesced and LDS-conflict-free (stride 65 mod 32 = 1).
    float* q_lds = smem_big;
    float* out2 = out + OUT_NCHW_OFF;   // NCHW
    float* out3 = out + OUT_NHWC_OFF;   // NHWC flat (float2-aligned)
    const float2* emb2 = reinterpret_cast<const float2*>(emb);
    float2* out3_2 = reinterpret_cast<float2*>(out3);

    for (int s = 0; s < 2; ++s) {
        __syncthreads();   // (s=0: also publishes is_last; q_lds free to reuse)
#pragma unroll
        for (int it = 0; it < 8; ++it) {
            int fid = it * 256 + t;
            int pp  = fid >> 5;
            int c2  = fid & 31;
            int row = idx_lds[s * 64 + pp];
            float2 v = emb2[row * 32 + c2];
            out3_2[(size_t)(pix0 + s * 64 + pp) * 32 + c2] = v;
            q_lds[pp * 65 + c2 * 2 + 0] = v.x;
            q_lds[pp * 65 + c2 * 2 + 1] = v.y;
        }
        __syncthreads();
#pragma unroll
        for (int it = 0; it < 16; ++it) {
            int did = it * 256 + t;
            int c   = did >> 6;
            int hwl = did & 63;
            out2[(size_t)(b * DDIM + c) * HWSZ + hwb + s * 64 + hwl] = q_lds[hwl * 65 + c];
        }
    }

    // Last block computes loss + perplexity (fused vq_fin). Counts/loss were
    // published by every block before its ticket add (syncthreads drained the
    // agent-scope atomics); read back with agent-scope atomic loads.
    __syncthreads();
    if (is_last) {
        double s = 0.0;
        for (int k = t; k < KCODES; k += 256) {
            unsigned cv = __hip_atomic_load(gcnt + k, __ATOMIC_RELAXED,
                                            __HIP_MEMORY_SCOPE_AGENT);
            double p = (double)cv / (double)NPIX;
            s += p * log(p + 1e-10);
        }
#pragma unroll
        for (int o = 32; o > 0; o >>= 1) s += __shfl_xor(s, o, 64);
        if ((t & 63) == 0) rd[t >> 6] = s;
        __syncthreads();
        if (t == 0) {
            double tot = rd[0] + rd[1] + rd[2] + rd[3];
            out[OUT_PERP_IDX] = (float)exp(-tot);
            float lossv = __hip_atomic_load(ws, __ATOMIC_RELAXED,
                                            __HIP_MEMORY_SCOPE_AGENT);
            out[0] = 0.25f * lossv / (float)NELEM;
        }
    }
}

extern "C" void kernel_launch(void* const* d_in, const int* in_sizes, int n_in,
                              void* d_out, int out_size, void* d_ws, size_t ws_size,
                              hipStream_t stream) {
    const float* in  = (const float*)d_in[0];
    const float* emb = (const float*)d_in[1];
    float* out = (float*)d_out;
    float* ws  = (float*)d_ws;

    // vq_prep zeroes loss+counts+ticket and overwrites norms + frag region.
    vq_prep<<<32, 256, 0, stream>>>(emb, ws);
    vq_main<<<NBLOCKS, 256, 0, stream>>>(in, emb, out, ws);
}

// Round 4
// 155.544 us; speedup vs baseline: 1.0012x; 1.0012x over previous
//
#include <hip/hip_runtime.h>
#include <math.h>

// Problem constants
#define NPIX   131072      // 32 * 64 * 64 pixels
#define KCODES 512
#define DDIM   64
#define HWSZ   4096        // 64*64
#define NELEM  8388608     // NPIX * DDIM

// d_out layout (fp32): [0]=loss, [1..1+NELEM)=q_nchw, [1+NELEM]=perplexity,
// [2+NELEM .. 2+2*NELEM)=q_nhwc flat
#define OUT_NCHW_OFF 1
#define OUT_PERP_IDX (1 + NELEM)
#define OUT_NHWC_OFF (2 + NELEM)

// ws layout (fp32 words): [0]=loss, [16..528)=|e|^2, [544..1056)=counts(uint),
// [1056]=ticket, [2048..) = e bf16 hi/lo fragments in MFMA B-layout (128KB)
#define WS_NRM_OFF  16
#define WS_CNT_OFF  544
#define WS_TICKET   1056
#define WS_FRAG_F32 2048

#define NBLOCKS (NPIX / 128)   // 1024 blocks, 128 pixels each

typedef __bf16 bf16x8 __attribute__((ext_vector_type(8)));
typedef float  f32x4  __attribute__((ext_vector_type(4)));

// Fused prep (memset + norms + pack in one dispatch). Thread tid =
// [ctile(32)][kstep(2)][h(2)][lane(64)] packs e into bf16 hi/lo MFMA
// B-fragments (16x16x32: B[k][n], n=lane&15, k=(lane>>4)*8+j); 16B coalesced.
// tid<512 computes |e|^2; tid in [512,1024) zeros counts; tid 0 zeros loss;
// tid 1024 zeros the last-block ticket.
__global__ __launch_bounds__(256) void vq_prep(const float* __restrict__ emb,
                                               float* __restrict__ ws) {
    int tid  = blockIdx.x * 256 + threadIdx.x;   // 0..8191
    if (tid == 0) ws[0] = 0.f;
    if (tid == 2 * KCODES) reinterpret_cast<unsigned*>(ws)[WS_TICKET] = 0u;
    if (tid < KCODES) {
        const float4* e4 = reinterpret_cast<const float4*>(emb + tid * DDIM);
        float s = 0.f;
#pragma unroll
        for (int i = 0; i < 16; ++i) {
            float4 v = e4[i];
            s = fmaf(v.x, v.x, s); s = fmaf(v.y, v.y, s);
            s = fmaf(v.z, v.z, s); s = fmaf(v.w, v.w, s);
        }
        ws[WS_NRM_OFF + tid] = s;
    } else if (tid < 2 * KCODES) {
        reinterpret_cast<unsigned*>(ws)[WS_CNT_OFF + (tid - KCODES)] = 0u;
    }

    int lane = tid & 63;
    int h    = (tid >> 6) & 1;
    int ks   = (tid >> 7) & 1;
    int ct   = tid >> 8;                         // 0..31
    int code = ct * 16 + (lane & 15);
    int d0   = ks * 32 + ((lane >> 4) & 3) * 8;
    const float* src = emb + code * DDIM + d0;
    unsigned short us[8];
#pragma unroll
    for (int j = 0; j < 8; ++j) {
        float f = src[j];
        __bf16 hb = (__bf16)f;                       // RTN
        if (h == 0) {
            us[j] = __builtin_bit_cast(unsigned short, hb);
        } else {
            __bf16 lb = (__bf16)(f - (float)hb);
            us[j] = __builtin_bit_cast(unsigned short, lb);
        }
    }
    uint4 v;
    v.x = us[0] | ((unsigned)us[1] << 16);
    v.y = us[2] | ((unsigned)us[3] << 16);
    v.z = us[4] | ((unsigned)us[5] << 16);
    v.w = us[6] | ((unsigned)us[7] << 16);
    reinterpret_cast<uint4*>(ws + WS_FRAG_F32)[tid] = v;
}

// Main. Lessons: R1 — (256,4) reg-cap spills the full-tile live set; R2 —
// single-buffered B exposes L2 latency every chunk; R3 — LDS-staged B costs a
// per-chunk __syncthreads whose implied vmcnt(0) drain serializes all waves
// (the m97 barrier-drain trap). R4 combines the two proven winners: the
// 1024-block grid (4 blocks/CU available; R0/R2's 512-block grid capped the
// CU at 8 waves) with R0's barrier-free REGISTER double-buffered B inner
// loop (B frag table = 128KB, L2-resident). Per-wave live set ~145 regs ->
// (256,3): 170-reg cap, 3-4 blocks/CU, no spill. All arithmetic, accumulation
// order, and argmin tie-breaks token-identical to the passing kernels.
__global__ __launch_bounds__(256, 3) void vq_main(const float* __restrict__ in,
                                                  const float* __restrict__ emb,
                                                  float* __restrict__ out,
                                                  float* __restrict__ ws) {
    __shared__ __align__(16) float q_lds[64 * 65];   // epilogue transpose tile
    __shared__ float    x2_lds[128];
    __shared__ float    nrm_lds[KCODES];
    __shared__ int      idx_lds[128];
    __shared__ unsigned cnt_lds[KCODES];
    __shared__ float    red_tot;
    __shared__ int      is_last;
    __shared__ double   rd[4];

    const int t = threadIdx.x;
    const int l = t & 63, wid = t >> 6;   // wave handles pixels [wid*32, +32)
    cnt_lds[t] = 0u; cnt_lds[t + 256] = 0u;
    if (t == 0) red_tot = 0.f;

    const int pix0 = blockIdx.x << 7;     // 128 px per block
    const int b    = pix0 >> 12;
    const int hwb  = pix0 & (HWSZ - 1);

    nrm_lds[t]       = ws[WS_NRM_OFF + t];
    nrm_lds[t + 256] = ws[WS_NRM_OFF + t + 256];

    // A-fragments (A[m][k]: m=lane&15, k=(lane>>4)*8+j), hi/lo bf16 split,
    // loaded straight from global NCHW. |x|^2 via xor-16/32 reduce
    // (lanes l, l^16, l^32, l^48 cover all 64 channels of pixel hw).
    const float* base = in + b * (DDIM * HWSZ) + hwb + wid * 32;
    bf16x8 a_hi[2][2], a_lo[2][2];
    float x2p[2];
#pragma unroll
    for (int pt = 0; pt < 2; ++pt) {
        const int hw = pt * 16 + (l & 15);
        float s = 0.f;
#pragma unroll
        for (int ks = 0; ks < 2; ++ks) {
            const int d0 = ks * 32 + ((l >> 4) & 3) * 8;
            const float* pp = base + hw + d0 * HWSZ;
            bf16x8 h8, l8;
#pragma unroll
            for (int j = 0; j < 8; ++j) {
                float f = pp[j * HWSZ];
                s = fmaf(f, f, s);
                __bf16 hb = (__bf16)f;
                h8[j] = hb;
                l8[j] = (__bf16)(f - (float)hb);
            }
            a_hi[pt][ks] = h8; a_lo[pt][ks] = l8;
        }
        s += __shfl_xor(s, 16, 64);
        s += __shfl_xor(s, 32, 64);
        x2p[pt] = s;
    }
    if (l < 16) {
        x2_lds[wid * 32 + l]      = x2p[0];
        x2_lds[wid * 32 + 16 + l] = x2p[1];
    }
    __syncthreads();   // nrm_lds + cnt_lds + red_tot ready for all waves

    const uint4* fragp = reinterpret_cast<const uint4*>(ws + WS_FRAG_F32);
    float best[2][4]; int bidx[2][4];
#pragma unroll
    for (int pt = 0; pt < 2; ++pt)
#pragma unroll
    for (int r = 0; r < 4; ++r) { best[pt][r] = 3.4e38f; bidx[pt][r] = 0; }

    // B-frag register double buffer: 8 frags/chunk = [ct][ks][h]; no barriers
    // in the chunk loop — waves free-run, prefetch covers L2 latency.
    uint4 bcur[8], bnxt[8];
#pragma unroll
    for (int i = 0; i < 8; ++i) {
        int ct = i >> 2, ks = (i >> 1) & 1, h = i & 1;
        bcur[i] = fragp[(((ct) * 2 + ks) * 2 + h) * 64 + l];
    }

#pragma unroll 1
    for (int c = 0; c < 16; ++c) {
        const int ctb = c << 1;
        if (c + 1 < 16) {
#pragma unroll
            for (int i = 0; i < 8; ++i) {
                int ct = i >> 2, ks = (i >> 1) & 1, h = i & 1;
                bnxt[i] = fragp[(((ctb + 2 + ct) * 2 + ks) * 2 + h) * 64 + l];
            }
        }
        // 32 pix x 32 codes: 4 C-tiles, 4-term bf16 split accumulated in fp32
        f32x4 acc[2][2];
#pragma unroll
        for (int pt = 0; pt < 2; ++pt)
#pragma unroll
        for (int ct = 0; ct < 2; ++ct) {
            f32x4 a = {0.f, 0.f, 0.f, 0.f};
#pragma unroll
            for (int ks = 0; ks < 2; ++ks) {
                bf16x8 bh = __builtin_bit_cast(bf16x8, bcur[ct * 4 + ks * 2 + 0]);
                bf16x8 bl = __builtin_bit_cast(bf16x8, bcur[ct * 4 + ks * 2 + 1]);
                a = __builtin_amdgcn_mfma_f32_16x16x32_bf16(a_hi[pt][ks], bh, a, 0, 0, 0);
                a = __builtin_amdgcn_mfma_f32_16x16x32_bf16(a_hi[pt][ks], bl, a, 0, 0, 0);
                a = __builtin_amdgcn_mfma_f32_16x16x32_bf16(a_lo[pt][ks], bh, a, 0, 0, 0);
                a = __builtin_amdgcn_mfma_f32_16x16x32_bf16(a_lo[pt][ks], bl, a, 0, 0, 0);
            }
            acc[pt][ct] = a;
        }
        // argmin update; C/D: col(code)=lane&15, row(pix)=(lane>>4)*4+reg
        const int cb = c << 5;
#pragma unroll
        for (int ct = 0; ct < 2; ++ct) {
            int code = cb + ct * 16 + (l & 15);
            float nv = nrm_lds[code];
#pragma unroll
            for (int pt = 0; pt < 2; ++pt)
#pragma unroll
            for (int r = 0; r < 4; ++r) {
                float d = fmaf(-2.f, acc[pt][ct][r], nv);
                if (d < best[pt][r]) { best[pt][r] = d; bidx[pt][r] = code; }
            }
        }
#pragma unroll
        for (int i = 0; i < 8; ++i) bcur[i] = bnxt[i];
    }

    // Cross-lane argmin within each 16-lane group (codes spread over lane&15);
    // (dist, then idx) min = exact first-min semantics.
#pragma unroll
    for (int off = 1; off < 16; off <<= 1) {
#pragma unroll
        for (int pt = 0; pt < 2; ++pt)
#pragma unroll
        for (int r = 0; r < 4; ++r) {
            float ob = __shfl_xor(best[pt][r], off, 64);
            int   oi = __shfl_xor(bidx[pt][r], off, 64);
            bool take = (ob < best[pt][r]) || (ob == best[pt][r] && oi < bidx[pt][r]);
            if (take) { best[pt][r] = ob; bidx[pt][r] = oi; }
        }
    }
    if ((l & 15) == 0) {
        int q = l >> 4;
        float lp = 0.f;
#pragma unroll
        for (int pt = 0; pt < 2; ++pt)
#pragma unroll
        for (int r = 0; r < 4; ++r) {
            int pixl = wid * 32 + pt * 16 + q * 4 + r;
            idx_lds[pixl] = bidx[pt][r];
            atomicAdd(&cnt_lds[bidx[pt][r]], 1u);
            lp += x2_lds[pixl] + best[pt][r];   // |x-e|^2 = x^2 + (|e|^2 - 2x.e)
        }
        atomicAdd(&red_tot, lp);
    }
    __syncthreads();

    if (t == 0) atomicAdd(ws, red_tot);
    unsigned* gcnt = reinterpret_cast<unsigned*>(ws) + WS_CNT_OFF;
    atomicAdd(gcnt + t, cnt_lds[t]);
    atomicAdd(gcnt + t + 256, cnt_lds[t + 256]);
    __syncthreads();   // all this block's global atomics drained

    if (t == 0) {
        unsigned tk = __hip_atomic_fetch_add(
            reinterpret_cast<unsigned*>(ws) + WS_TICKET, 1u,
            __ATOMIC_ACQ_REL, __HIP_MEMORY_SCOPE_AGENT);
        is_last = (tk == NBLOCKS - 1);
    }

    // Epilogue: padded LDS tile makes both NHWC and NCHW writes coalesced and
    // LDS-conflict-free (stride 65 mod 32 = 1).
    float* out2 = out + OUT_NCHW_OFF;   // NCHW
    float* out3 = out + OUT_NHWC_OFF;   // NHWC flat (float2-aligned)
    const float2* emb2 = reinterpret_cast<const float2*>(emb);
    float2* out3_2 = reinterpret_cast<float2*>(out3);

    for (int s = 0; s < 2; ++s) {
        __syncthreads();   // s=0: also publishes is_last; s=1: q_lds reuse safe
#pragma unroll
        for (int it = 0; it < 8; ++it) {
            int fid = it * 256 + t;
            int pp  = fid >> 5;
            int c2  = fid & 31;
            int row = idx_lds[s * 64 + pp];
            float2 v = emb2[row * 32 + c2];
            out3_2[(size_t)(pix0 + s * 64 + pp) * 32 + c2] = v;
            q_lds[pp * 65 + c2 * 2 + 0] = v.x;
            q_lds[pp * 65 + c2 * 2 + 1] = v.y;
        }
        __syncthreads();
#pragma unroll
        for (int it = 0; it < 16; ++it) {
            int did = it * 256 + t;
            int c   = did >> 6;
            int hwl = did & 63;
            out2[(size_t)(b * DDIM + c) * HWSZ + hwb + s * 64 + hwl] = q_lds[hwl * 65 + c];
        }
    }

    // Last block computes loss + perplexity (fused vq_fin). Counts/loss were
    // published by every block before its ticket add; read back with
    // agent-scope atomic loads.
    __syncthreads();
    if (is_last) {
        double s = 0.0;
        for (int k = t; k < KCODES; k += 256) {
            unsigned cv = __hip_atomic_load(gcnt + k, __ATOMIC_RELAXED,
                                            __HIP_MEMORY_SCOPE_AGENT);
            double p = (double)cv / (double)NPIX;
            s += p * log(p + 1e-10);
        }
#pragma unroll
        for (int o = 32; o > 0; o >>= 1) s += __shfl_xor(s, o, 64);
        if ((t & 63) == 0) rd[t >> 6] = s;
        __syncthreads();
        if (t == 0) {
            double tot = rd[0] + rd[1] + rd[2] + rd[3];
            out[OUT_PERP_IDX] = (float)exp(-tot);
            float lossv = __hip_atomic_load(ws, __ATOMIC_RELAXED,
                                            __HIP_MEMORY_SCOPE_AGENT);
            out[0] = 0.25f * lossv / (float)NELEM;
        }
    }
}

extern "C" void kernel_launch(void* const* d_in, const int* in_sizes, int n_in,
                              void* d_out, int out_size, void* d_ws, size_t ws_size,
                              hipStream_t stream) {
    const float* in  = (const float*)d_in[0];
    const float* emb = (const float*)d_in[1];
    float* out = (float*)d_out;
    float* ws  = (float*)d_ws;

    // vq_prep zeroes loss+counts+ticket and overwrites norms + frag region.
    vq_prep<<<32, 256, 0, stream>>>(emb, ws);
    vq_main<<<NBLOCKS, 256, 0, stream>>>(in, emb, out, ws);
}

// Round 5
// 135.256 us; speedup vs baseline: 1.1514x; 1.1500x over previous
//
#include <hip/hip_runtime.h>
#include <math.h>

// Problem constants
#define NPIX   131072      // 32 * 64 * 64 pixels
#define KCODES 512
#define DDIM   64
#define HWSZ   4096        // 64*64
#define NELEM  8388608     // NPIX * DDIM

// d_out layout (fp32): [0]=loss, [1..1+NELEM)=q_nchw, [1+NELEM]=perplexity,
// [2+NELEM .. 2+2*NELEM)=q_nhwc flat
#define OUT_NCHW_OFF 1
#define OUT_PERP_IDX (1 + NELEM)
#define OUT_NHWC_OFF (2 + NELEM)

// ws layout (fp32 words): [0]=loss, [16..528)=|e|^2, [544..1056)=counts(uint),
// [1056]=ticket, [2048..) = e bf16 hi/lo fragments in MFMA B-layout (128KB)
#define WS_NRM_OFF  16
#define WS_CNT_OFF  544
#define WS_TICKET   1056
#define WS_FRAG_F32 2048

#define NBLOCKS 256            // 512 px/block, 1 block per CU

typedef __bf16 bf16x8 __attribute__((ext_vector_type(8)));
typedef float  f32x4  __attribute__((ext_vector_type(4)));

__device__ __forceinline__ void glds16(const void* g, void* l) {
    __builtin_amdgcn_global_load_lds(
        (const __attribute__((address_space(1))) void*)g,
        (__attribute__((address_space(3))) void*)l, 16, 0, 0);
}

// Fused prep (memset + norms + pack in one dispatch). Thread tid =
// [ctile(32)][kstep(2)][h(2)][lane(64)] packs e into bf16 hi/lo MFMA
// B-fragments (16x16x32: B[k][n], n=lane&15, k=(lane>>4)*8+j); 16B coalesced.
// tid<512 computes |e|^2; tid in [512,1024) zeros counts; tid 0 zeros loss;
// tid 1024 zeros the last-block ticket.
__global__ __launch_bounds__(256) void vq_prep(const float* __restrict__ emb,
                                               float* __restrict__ ws) {
    int tid  = blockIdx.x * 256 + threadIdx.x;   // 0..8191
    if (tid == 0) ws[0] = 0.f;
    if (tid == 2 * KCODES) reinterpret_cast<unsigned*>(ws)[WS_TICKET] = 0u;
    if (tid < KCODES) {
        const float4* e4 = reinterpret_cast<const float4*>(emb + tid * DDIM);
        float s = 0.f;
#pragma unroll
        for (int i = 0; i < 16; ++i) {
            float4 v = e4[i];
            s = fmaf(v.x, v.x, s); s = fmaf(v.y, v.y, s);
            s = fmaf(v.z, v.z, s); s = fmaf(v.w, v.w, s);
        }
        ws[WS_NRM_OFF + tid] = s;
    } else if (tid < 2 * KCODES) {
        reinterpret_cast<unsigned*>(ws)[WS_CNT_OFF + (tid - KCODES)] = 0u;
    }

    int lane = tid & 63;
    int h    = (tid >> 6) & 1;
    int ks   = (tid >> 7) & 1;
    int ct   = tid >> 8;                         // 0..31
    int code = ct * 16 + (lane & 15);
    int d0   = ks * 32 + ((lane >> 4) & 3) * 8;
    const float* src = emb + code * DDIM + d0;
    unsigned short us[8];
#pragma unroll
    for (int j = 0; j < 8; ++j) {
        float f = src[j];
        __bf16 hb = (__bf16)f;                       // RTN
        if (h == 0) {
            us[j] = __builtin_bit_cast(unsigned short, hb);
        } else {
            __bf16 lb = (__bf16)(f - (float)hb);
            us[j] = __builtin_bit_cast(unsigned short, lb);
        }
    }
    uint4 v;
    v.x = us[0] | ((unsigned)us[1] << 16);
    v.y = us[2] | ((unsigned)us[3] << 16);
    v.z = us[4] | ((unsigned)us[5] << 16);
    v.w = us[6] | ((unsigned)us[7] << 16);
    reinterpret_cast<uint4*>(ws + WS_FRAG_F32)[tid] = v;
}

// Main. Evidence R0-R4: perf tracks MFMA-per-B-load amortization (pt=4 best),
// NOT wave count; every wave re-reading the 128KB B table from L2 is the
// bottleneck. R5: keep the WHOLE B frag table resident in LDS (loaded once
// per block via global_load_lds; gfx950 allows >64KB/block — R0 ran 76KB,
// HK uses 128KB). 256 blocks x 512 threads (8 waves x 64 px, pt=4),
// 1 block/CU, ~152KB LDS. Chunk loop is barrier-free ds_read+MFMA (B is
// read-only after one staging barrier); waves free-run so argmin VALU of one
// wave overlaps MFMA of another. Inner-loop arithmetic/accumulation order/
// tie-breaks token-identical to R0 -> identical argmin -> identical outputs.
__global__ __launch_bounds__(512, 2) void vq_main(const float* __restrict__ in,
                                                  const float* __restrict__ emb,
                                                  float* __restrict__ out,
                                                  float* __restrict__ ws) {
    __shared__ __align__(16) char  B_lds[131072];    // full bf16 hi/lo frag table
    __shared__ __align__(16) float q_lds[64 * 65];   // epilogue transpose tile
    __shared__ float    x2_lds[512];
    __shared__ float    nrm_lds[KCODES];
    __shared__ int      idx_lds[512];
    __shared__ unsigned cnt_lds[KCODES];
    __shared__ float    red_tot;
    __shared__ int      is_last;
    __shared__ double   rd[8];

    const int t = threadIdx.x;            // 0..511
    const int l = t & 63, wid = t >> 6;   // 8 waves; wave owns px [wid*64,+64)

    const int pix0 = blockIdx.x << 9;     // 512 px per block
    const int b    = pix0 >> 12;
    const int hwb  = pix0 & (HWSZ - 1);

    // Issue the full B-table stage FIRST (async DMA, no VGPRs): 16 rounds x
    // 512 thr x 16B = 128KB. LDS dest is linear in lane (base + t*16) ->
    // satisfies the wave-uniform-base + lane*16 constraint.
    const char* fragbytes = reinterpret_cast<const char*>(ws + WS_FRAG_F32);
#pragma unroll
    for (int r = 0; r < 16; ++r)
        glds16(fragbytes + r * 8192 + t * 16, B_lds + r * 8192 + t * 16);

    cnt_lds[t] = 0u;
    if (t == 0) red_tot = 0.f;
    nrm_lds[t] = ws[WS_NRM_OFF + t];

    // A-fragments (A[m][k]: m=lane&15, k=(lane>>4)*8+j), hi/lo bf16 split,
    // loaded straight from global NCHW (hides under the B-stage DMA).
    // |x|^2 via xor-16/32 reduce (lanes l,l^16,l^32,l^48 cover 64 channels).
    const float* base = in + b * (DDIM * HWSZ) + hwb + wid * 64;
    bf16x8 a_hi[4][2], a_lo[4][2];
    float x2p[4];
#pragma unroll
    for (int pt = 0; pt < 4; ++pt) {
        const int hw = pt * 16 + (l & 15);
        float s = 0.f;
#pragma unroll
        for (int ks = 0; ks < 2; ++ks) {
            const int d0 = ks * 32 + ((l >> 4) & 3) * 8;
            const float* pp = base + hw + d0 * HWSZ;
            bf16x8 h8, l8;
#pragma unroll
            for (int j = 0; j < 8; ++j) {
                float f = pp[j * HWSZ];
                s = fmaf(f, f, s);
                __bf16 hb = (__bf16)f;
                h8[j] = hb;
                l8[j] = (__bf16)(f - (float)hb);
            }
            a_hi[pt][ks] = h8; a_lo[pt][ks] = l8;
        }
        s += __shfl_xor(s, 16, 64);
        s += __shfl_xor(s, 32, 64);
        x2p[pt] = s;
    }
    if (l < 16) {
#pragma unroll
        for (int pt = 0; pt < 4; ++pt) x2_lds[wid * 64 + pt * 16 + l] = x2p[pt];
    }
    __syncthreads();   // B-table staged (barrier drains vmcnt); lds scalars ready

    float best[4][4]; int bidx[4][4];
#pragma unroll
    for (int pt = 0; pt < 4; ++pt)
#pragma unroll
    for (int r = 0; r < 4; ++r) { best[pt][r] = 3.4e38f; bidx[pt][r] = 0; }

    // Barrier-free chunk loop: B frags from LDS (linear lane*16 -> conflict-
    // free), register double-buffer one chunk ahead (ds_read ~12cyc hidden
    // under 64 MFMA/chunk). 8 frags/chunk = [ct][ks][h].
    uint4 bcur[8], bnxt[8];
#pragma unroll
    for (int i = 0; i < 8; ++i)
        bcur[i] = *reinterpret_cast<const uint4*>(B_lds + (i << 10) + (l << 4));

#pragma unroll 1
    for (int c = 0; c < 16; ++c) {
        if (c + 1 < 16) {
#pragma unroll
            for (int i = 0; i < 8; ++i)
                bnxt[i] = *reinterpret_cast<const uint4*>(
                    B_lds + ((c + 1) << 13) + (i << 10) + (l << 4));
        }
        // 64 pix x 32 codes: 8 C-tiles, 4-term bf16 split accumulated in fp32
        f32x4 acc[4][2];
#pragma unroll
        for (int pt = 0; pt < 4; ++pt)
#pragma unroll
        for (int ct = 0; ct < 2; ++ct) {
            f32x4 a = {0.f, 0.f, 0.f, 0.f};
#pragma unroll
            for (int ks = 0; ks < 2; ++ks) {
                bf16x8 bh = __builtin_bit_cast(bf16x8, bcur[ct * 4 + ks * 2 + 0]);
                bf16x8 bl = __builtin_bit_cast(bf16x8, bcur[ct * 4 + ks * 2 + 1]);
                a = __builtin_amdgcn_mfma_f32_16x16x32_bf16(a_hi[pt][ks], bh, a, 0, 0, 0);
                a = __builtin_amdgcn_mfma_f32_16x16x32_bf16(a_hi[pt][ks], bl, a, 0, 0, 0);
                a = __builtin_amdgcn_mfma_f32_16x16x32_bf16(a_lo[pt][ks], bh, a, 0, 0, 0);
                a = __builtin_amdgcn_mfma_f32_16x16x32_bf16(a_lo[pt][ks], bl, a, 0, 0, 0);
            }
            acc[pt][ct] = a;
        }
        // argmin update; C/D: col(code)=lane&15, row(pix)=(lane>>4)*4+reg
        const int cb = c << 5;
#pragma unroll
        for (int ct = 0; ct < 2; ++ct) {
            int code = cb + ct * 16 + (l & 15);
            float nv = nrm_lds[code];
#pragma unroll
            for (int pt = 0; pt < 4; ++pt)
#pragma unroll
            for (int r = 0; r < 4; ++r) {
                float d = fmaf(-2.f, acc[pt][ct][r], nv);
                if (d < best[pt][r]) { best[pt][r] = d; bidx[pt][r] = code; }
            }
        }
#pragma unroll
        for (int i = 0; i < 8; ++i) bcur[i] = bnxt[i];
    }

    // Cross-lane argmin within each 16-lane group (codes spread over lane&15);
    // (dist, then idx) min = exact first-min semantics.
#pragma unroll
    for (int off = 1; off < 16; off <<= 1) {
#pragma unroll
        for (int pt = 0; pt < 4; ++pt)
#pragma unroll
        for (int r = 0; r < 4; ++r) {
            float ob = __shfl_xor(best[pt][r], off, 64);
            int   oi = __shfl_xor(bidx[pt][r], off, 64);
            bool take = (ob < best[pt][r]) || (ob == best[pt][r] && oi < bidx[pt][r]);
            if (take) { best[pt][r] = ob; bidx[pt][r] = oi; }
        }
    }
    if ((l & 15) == 0) {
        int q = l >> 4;
        float lp = 0.f;
#pragma unroll
        for (int pt = 0; pt < 4; ++pt)
#pragma unroll
        for (int r = 0; r < 4; ++r) {
            int pixl = wid * 64 + pt * 16 + q * 4 + r;
            idx_lds[pixl] = bidx[pt][r];
            atomicAdd(&cnt_lds[bidx[pt][r]], 1u);
            lp += x2_lds[pixl] + best[pt][r];   // |x-e|^2 = x^2 + (|e|^2 - 2x.e)
        }
        atomicAdd(&red_tot, lp);
    }
    __syncthreads();

    if (t == 0) atomicAdd(ws, red_tot);
    unsigned* gcnt = reinterpret_cast<unsigned*>(ws) + WS_CNT_OFF;
    atomicAdd(gcnt + t, cnt_lds[t]);
    __syncthreads();   // all this block's global atomics drained

    if (t == 0) {
        unsigned tk = __hip_atomic_fetch_add(
            reinterpret_cast<unsigned*>(ws) + WS_TICKET, 1u,
            __ATOMIC_ACQ_REL, __HIP_MEMORY_SCOPE_AGENT);
        is_last = (tk == NBLOCKS - 1);
    }

    // Epilogue: padded LDS tile makes both NHWC and NCHW writes coalesced and
    // LDS-conflict-free (stride 65 mod 32 = 1). 8 slices of 64 px.
    float* out2 = out + OUT_NCHW_OFF;   // NCHW
    float* out3 = out + OUT_NHWC_OFF;   // NHWC flat (float2-aligned)
    const float2* emb2 = reinterpret_cast<const float2*>(emb);
    float2* out3_2 = reinterpret_cast<float2*>(out3);

    for (int s = 0; s < 8; ++s) {
        __syncthreads();   // s=0: also publishes is_last; else: q_lds reuse safe
#pragma unroll
        for (int it = 0; it < 4; ++it) {
            int fid = it * 512 + t;            // 64px x 32 float2 = 2048
            int pp  = fid >> 5;
            int c2  = fid & 31;
            int row = idx_lds[s * 64 + pp];
            float2 v = emb2[row * 32 + c2];
            out3_2[(size_t)(pix0 + s * 64 + pp) * 32 + c2] = v;
            q_lds[pp * 65 + c2 * 2 + 0] = v.x;
            q_lds[pp * 65 + c2 * 2 + 1] = v.y;
        }
        __syncthreads();
#pragma unroll
        for (int it = 0; it < 8; ++it) {
            int did = it * 512 + t;            // 64c x 64px = 4096
            int c   = did >> 6;
            int hwl = did & 63;
            out2[(size_t)(b * DDIM + c) * HWSZ + hwb + s * 64 + hwl] = q_lds[hwl * 65 + c];
        }
    }

    // Last block computes loss + perplexity (fused vq_fin). Counts/loss were
    // published by every block before its ticket add; read back with
    // agent-scope atomic loads.
    __syncthreads();
    if (is_last) {
        double s = 0.0;
        for (int k = t; k < KCODES; k += 512) {
            unsigned cv = __hip_atomic_load(gcnt + k, __ATOMIC_RELAXED,
                                            __HIP_MEMORY_SCOPE_AGENT);
            double p = (double)cv / (double)NPIX;
            s += p * log(p + 1e-10);
        }
#pragma unroll
        for (int o = 32; o > 0; o >>= 1) s += __shfl_xor(s, o, 64);
        if ((t & 63) == 0) rd[t >> 6] = s;
        __syncthreads();
        if (t == 0) {
            double tot = rd[0] + rd[1] + rd[2] + rd[3]
                       + rd[4] + rd[5] + rd[6] + rd[7];
            out[OUT_PERP_IDX] = (float)exp(-tot);
            float lossv = __hip_atomic_load(ws, __ATOMIC_RELAXED,
                                            __HIP_MEMORY_SCOPE_AGENT);
            out[0] = 0.25f * lossv / (float)NELEM;
        }
    }
}

extern "C" void kernel_launch(void* const* d_in, const int* in_sizes, int n_in,
                              void* d_out, int out_size, void* d_ws, size_t ws_size,
                              hipStream_t stream) {
    const float* in  = (const float*)d_in[0];
    const float* emb = (const float*)d_in[1];
    float* out = (float*)d_out;
    float* ws  = (float*)d_ws;

    // vq_prep zeroes loss+counts+ticket and overwrites norms + frag region.
    vq_prep<<<32, 256, 0, stream>>>(emb, ws);
    vq_main<<<NBLOCKS, 512, 0, stream>>>(in, emb, out, ws);
}